// Round 1
// 836.959 us; speedup vs baseline: 1.0654x; 1.0654x over previous
//
#include <hip/hip_runtime.h>
#include <stdint.h>

#define VNUM 256
#define DNUM 512
#define BNUM 1024

typedef __attribute__((ext_vector_type(8))) short bf16x8;
typedef __attribute__((ext_vector_type(4))) float f32x4;

// RNE float -> bf16 (bit pattern)
__device__ __forceinline__ uint16_t f2bf(float f) {
    uint32_t u = __float_as_uint(f);
    uint32_t r = (u + 0x7FFFu + ((u >> 16) & 1u)) >> 16;
    return (uint16_t)r;
}

__device__ __forceinline__ void gl_lds16(const void* g, void* l) {
    __builtin_amdgcn_global_load_lds(
        (const __attribute__((address_space(1))) uint32_t*)g,
        (__attribute__((address_space(3))) uint32_t*)l, 16, 0, 0);
}

// stage this wave's 64-row x 32-k bf16 slice (256 x 16B chunks, 4 per lane)
// chunk c = p*64+l -> local row r=c>>2, slot k2=c&3 holds global k-chunk k2^((r>>1)&3)
__device__ __forceinline__ void stage_slice(const uint16_t* __restrict__ gbase,
                                            int kstride, uint16_t* lbase, int l) {
    #pragma unroll
    for (int p = 0; p < 4; p++) {
        const int c = p * 64 + l;
        const int r = c >> 2, k2 = c & 3;
        const int gk2 = k2 ^ ((r >> 1) & 3);
        gl_lds16(gbase + (size_t)r * kstride + gk2 * 8, lbase + p * 512);
    }
}

// ---------------------------------------------------------------- wx = x @ A^T
__global__ __launch_bounds__(256) void wx_kernel(const float* __restrict__ x,
                                                 const float* __restrict__ adj,
                                                 float* __restrict__ wx) {
    __shared__ float xs[64][36];
    __shared__ float as_[64][36];
    const int b0 = blockIdx.x * 64, i0 = blockIdx.y * 64;
    const int t = threadIdx.x;
    const int tx = t & 15, ty = t >> 4;
    const int lr = t >> 2, lk = (t & 3) * 8;
    float c[4][4] = {};
    for (int k0 = 0; k0 < 256; k0 += 32) {
        __syncthreads();
        *(float4*)&xs[lr][lk]      = *(const float4*)&x[(size_t)(b0 + lr) * VNUM + k0 + lk];
        *(float4*)&xs[lr][lk + 4]  = *(const float4*)&x[(size_t)(b0 + lr) * VNUM + k0 + lk + 4];
        *(float4*)&as_[lr][lk]     = *(const float4*)&adj[(size_t)(i0 + lr) * VNUM + k0 + lk];
        *(float4*)&as_[lr][lk + 4] = *(const float4*)&adj[(size_t)(i0 + lr) * VNUM + k0 + lk + 4];
        __syncthreads();
        #pragma unroll
        for (int kk = 0; kk < 32; kk++) {
            float xv[4], av[4];
            #pragma unroll
            for (int a = 0; a < 4; a++) xv[a] = xs[ty + a * 16][kk];
            #pragma unroll
            for (int b = 0; b < 4; b++) av[b] = as_[tx + b * 16][kk];
            #pragma unroll
            for (int a = 0; a < 4; a++)
                #pragma unroll
                for (int b = 0; b < 4; b++) c[a][b] += xv[a] * av[b];
        }
    }
    #pragma unroll
    for (int a = 0; a < 4; a++)
        #pragma unroll
        for (int b = 0; b < 4; b++)
            wx[(size_t)(b0 + ty + a * 16) * VNUM + i0 + tx + b * 16] = c[a][b];
}

// ---------------------------------------------------------------- x -> bf16
__global__ __launch_bounds__(256) void xcvt_kernel(const float* __restrict__ x,
                                                   uint16_t* __restrict__ xbf) {
    const int idx = (blockIdx.x * 256 + threadIdx.x) * 4;
    float4 v = *(const float4*)&x[idx];
    uint32_t p0 = (uint32_t)f2bf(v.x) | ((uint32_t)f2bf(v.y) << 16);
    uint32_t p1 = (uint32_t)f2bf(v.z) | ((uint32_t)f2bf(v.w) << 16);
    *(uint2*)&xbf[idx] = make_uint2(p0, p1);
}

// ---------------------------------------------------------------- W1 -> bf16 [V*D][256] + fp32 last col
// flat float4 walk over [V*D*257]; k==256 -> w1last
__global__ __launch_bounds__(256) void w1cvt_kernel(const float* __restrict__ W1,
                                                    uint16_t* __restrict__ W1bf,
                                                    float* __restrict__ w1last) {
    const uint32_t i4   = blockIdx.x * 256 + threadIdx.x;
    const uint32_t base = i4 * 4;
    float4 v = *(const float4*)&W1[base];
    float vv[4] = {v.x, v.y, v.z, v.w};
    #pragma unroll
    for (int j = 0; j < 4; j++) {
        uint32_t pos = base + j;
        uint32_t row = pos / 257u;          // magic-mul
        uint32_t k   = pos - row * 257u;
        if (k == 256u) w1last[row] = vv[j];
        else           W1bf[(size_t)row * 256 + k] = f2bf(vv[j]);
    }
}

// ---------------------------------------------------------------- W2 -> bf16
__global__ __launch_bounds__(256) void w2cvt_kernel(const float* __restrict__ W2,
                                                    uint16_t* __restrict__ W2bf) {
    const size_t idx = ((size_t)blockIdx.x * 256 + threadIdx.x) * 4;
    float4 v = *(const float4*)&W2[idx];
    uint32_t p0 = (uint32_t)f2bf(v.x) | ((uint32_t)f2bf(v.y) << 16);
    uint32_t p1 = (uint32_t)f2bf(v.z) | ((uint32_t)f2bf(v.w) << 16);
    *(uint2*)&W2bf[idx] = make_uint2(p0, p1);
}

// ---------------------------------------------------------------- fused per-variable MLP
// block = (var i, 64-row batch tile). 8 waves, each owns a 64-wide d-slice (ph1) / e-slice (ph2).
// phase1: C1[d][b] = W1[i] @ x^T  -> relu(+wx*w1last+b1) -> h1s (LDS, swizzled k-tiles)
// phase2: C2[b][e] = h1s @ W2[i]^T -> relu(+b2) . W3 -> out[b,i]
__global__ __launch_bounds__(512, 2) void fused_kernel(
        const uint16_t* __restrict__ xbf, const float* __restrict__ wx,
        const uint16_t* __restrict__ W1bf, const float* __restrict__ w1last,
        const float* __restrict__ b1, const uint16_t* __restrict__ W2bf,
        const float* __restrict__ b2, const float* __restrict__ W3,
        const float* __restrict__ b3, float* __restrict__ out) {

    __shared__ __align__(16) uint16_t h1s[16 * 64 * 32];   // 64 KB: [kt][b][32] swz; first 32 KB doubles as x-tile
    __shared__ __align__(16) uint16_t Ws[8 * 4096];        // 64 KB: per-wave double-buffered weight slices
    __shared__ float w1ls[DNUM], b1s[DNUM], b2s[DNUM], w3s[DNUM];
    __shared__ float wxs[64];
    __shared__ float red[8][64];

    // XCD-chunk swizzle: 4096 blocks, 8 XCDs -> 16 blocks of a var land on one XCD (W2[i] L2-resident)
    const int bid = blockIdx.x;
    const int swz = (bid & 7) * 512 + (bid >> 3);
    const int i   = swz >> 4;
    const int b0  = (swz & 15) * 64;

    const int t  = threadIdx.x;
    const int w  = t >> 6, l = t & 63;
    const int lo = l & 15, q = l >> 4;
    const int sA = (lo >> 1) & 3;

    w1ls[t] = w1last[(size_t)i * DNUM + t];
    b1s[t]  = b1[(size_t)i * DNUM + t];
    b2s[t]  = b2[(size_t)i * DNUM + t];
    w3s[t]  = W3[(size_t)i * DNUM + t];
    if (t < 64) wxs[t] = wx[(size_t)(b0 + t) * VNUM + i];

    // stage x tile [64][256] once, as 8 swizzled 32-k tiles, into h1s[0..16384)
    #pragma unroll
    for (int p = 0; p < 4; p++) {
        const int cb = p * 512 + w * 64;           // wave-uniform base chunk
        const int c  = cb + l;
        const int kt = c >> 8, cc = c & 255;
        const int r = cc >> 2, k2 = cc & 3;
        const int gk2 = k2 ^ ((r >> 1) & 3);
        gl_lds16(xbf + (size_t)(b0 + r) * VNUM + kt * 32 + gk2 * 8, &h1s[cb * 8]);
    }
    __syncthreads();

    uint16_t* myW = &Ws[w * 4096];
    const uint16_t* W1b = W1bf + ((size_t)i * DNUM + w * 64) * 256;
    const uint16_t* W2b = W2bf + ((size_t)i * DNUM + w * 64) * 512;

    f32x4 acc[4][4];
    #pragma unroll
    for (int a = 0; a < 4; a++)
        #pragma unroll
        for (int b = 0; b < 4; b++) { f32x4 z = {0.f, 0.f, 0.f, 0.f}; acc[a][b] = z; }

    // ---------------- phase 1: 8 K-steps, barrier-free per-wave dbuf pipeline
    stage_slice(W1b, 256, myW, l);
    #pragma unroll
    for (int kt = 0; kt < 8; kt++) {
        const int cur = (kt & 1) * 2048;
        if (kt < 7) stage_slice(W1b + (kt + 1) * 32, 256, myW + (((kt & 1) ^ 1) * 2048), l);
        if (kt < 7) asm volatile("s_waitcnt vmcnt(4)" ::: "memory");
        else        asm volatile("s_waitcnt vmcnt(0)" ::: "memory");
        bf16x8 af[4], bx[4];
        #pragma unroll
        for (int mt = 0; mt < 4; mt++)
            af[mt] = *(const bf16x8*)&myW[cur + (mt * 16 + lo) * 32 + (q ^ sA) * 8];
        #pragma unroll
        for (int nt = 0; nt < 4; nt++)
            bx[nt] = *(const bf16x8*)&h1s[kt * 2048 + (nt * 16 + lo) * 32 + (q ^ sA) * 8];
        __builtin_amdgcn_s_setprio(1);
        #pragma unroll
        for (int mt = 0; mt < 4; mt++)
            #pragma unroll
            for (int nt = 0; nt < 4; nt++)
                acc[mt][nt] = __builtin_amdgcn_mfma_f32_16x16x32_bf16(af[mt], bx[nt], acc[mt][nt], 0, 0, 0);
        __builtin_amdgcn_s_setprio(0);
        __builtin_amdgcn_sched_barrier(0);
    }

    __syncthreads();   // all waves done reading x tiles before overwriting that region

    // epilogue-1: h1 = relu(C1 + wx*w1last + b1); each lane packs 4 consecutive d -> one 8B swz store
    #pragma unroll
    for (int mt = 0; mt < 4; mt++) {
        const int dbase = w * 64 + mt * 16 + q * 4;
        const int ktile = dbase >> 5;
        const int dk    = dbase & 31;
        const int slot  = dk >> 3;
        const int sub   = dk & 7;           // 0 or 4
        #pragma unroll
        for (int nt = 0; nt < 4; nt++) {
            const int b = nt * 16 + lo;
            const float wxv = wxs[b];
            float v0 = acc[mt][nt][0] + wxv * w1ls[dbase + 0] + b1s[dbase + 0];
            float v1 = acc[mt][nt][1] + wxv * w1ls[dbase + 1] + b1s[dbase + 1];
            float v2 = acc[mt][nt][2] + wxv * w1ls[dbase + 2] + b1s[dbase + 2];
            float v3 = acc[mt][nt][3] + wxv * w1ls[dbase + 3] + b1s[dbase + 3];
            uint32_t lo32 = (uint32_t)f2bf(fmaxf(v0, 0.f)) | ((uint32_t)f2bf(fmaxf(v1, 0.f)) << 16);
            uint32_t hi32 = (uint32_t)f2bf(fmaxf(v2, 0.f)) | ((uint32_t)f2bf(fmaxf(v3, 0.f)) << 16);
            const int sslot = slot ^ sA;    // (b>>1)&3 == sA
            *(uint2*)&h1s[ktile * 2048 + b * 32 + sslot * 8 + sub] = make_uint2(lo32, hi32);
        }
    }
    #pragma unroll
    for (int a = 0; a < 4; a++)
        #pragma unroll
        for (int b = 0; b < 4; b++) { f32x4 z = {0.f, 0.f, 0.f, 0.f}; acc[a][b] = z; }
    __syncthreads();   // h1s fully written, visible to all waves

    // ---------------- phase 2: 16 K-steps; A from h1s (no staging), per-wave W2 dbuf
    stage_slice(W2b, 512, myW, l);
    #pragma unroll
    for (int kt = 0; kt < 16; kt++) {
        const int cur = (kt & 1) * 2048;
        if (kt < 15) stage_slice(W2b + (kt + 1) * 32, 512, myW + (((kt & 1) ^ 1) * 2048), l);
        if (kt < 15) asm volatile("s_waitcnt vmcnt(4)" ::: "memory");
        else         asm volatile("s_waitcnt vmcnt(0)" ::: "memory");
        bf16x8 ah[4], bw[4];
        #pragma unroll
        for (int mt = 0; mt < 4; mt++)
            ah[mt] = *(const bf16x8*)&h1s[kt * 2048 + (mt * 16 + lo) * 32 + (q ^ sA) * 8];
        #pragma unroll
        for (int nt = 0; nt < 4; nt++)
            bw[nt] = *(const bf16x8*)&myW[cur + (nt * 16 + lo) * 32 + (q ^ sA) * 8];
        __builtin_amdgcn_s_setprio(1);
        #pragma unroll
        for (int mt = 0; mt < 4; mt++)
            #pragma unroll
            for (int nt = 0; nt < 4; nt++)
                acc[mt][nt] = __builtin_amdgcn_mfma_f32_16x16x32_bf16(ah[mt], bw[nt], acc[mt][nt], 0, 0, 0);
        __builtin_amdgcn_s_setprio(0);
        __builtin_amdgcn_sched_barrier(0);
    }

    // epilogue-2: fused layer 3, out[b,i] = sum_e relu(C2+b2)*w3 + b3 (single owner -> plain store)
    #pragma unroll
    for (int mt = 0; mt < 4; mt++) {
        #pragma unroll
        for (int reg = 0; reg < 4; reg++) {
            float v = 0.f;
            #pragma unroll
            for (int nt = 0; nt < 4; nt++) {
                const int e = w * 64 + nt * 16 + lo;
                float h = acc[mt][nt][reg] + b2s[e];
                h = fmaxf(h, 0.f);
                v += h * w3s[e];
            }
            v += __shfl_xor(v, 1, 64);
            v += __shfl_xor(v, 2, 64);
            v += __shfl_xor(v, 4, 64);
            v += __shfl_xor(v, 8, 64);
            if (lo == 0) red[w][mt * 16 + q * 4 + reg] = v;
        }
    }
    __syncthreads();
    if (t < 64) {
        float v = b3[i];
        #pragma unroll
        for (int ww = 0; ww < 8; ww++) v += red[ww][t];
        out[(size_t)(b0 + t) * VNUM + i] = v;
    }
}

// ----------------------------------------------------------------
extern "C" void kernel_launch(void* const* d_in, const int* in_sizes, int n_in,
                              void* d_out, int out_size, void* d_ws, size_t ws_size,
                              hipStream_t stream) {
    const float* x   = (const float*)d_in[0];
    const float* adj = (const float*)d_in[1];
    const float* W1  = (const float*)d_in[2];
    const float* b1  = (const float*)d_in[3];
    const float* W2  = (const float*)d_in[4];
    const float* b2  = (const float*)d_in[5];
    const float* W3  = (const float*)d_in[6];
    const float* b3  = (const float*)d_in[7];
    float* out = (float*)d_out;

    // workspace: wx 1MB | xbf 0.5MB | w1last 0.5MB | W1bf 67MB | W2bf 134MB  (h1 eliminated)
    char* ws = (char*)d_ws;
    float*    wx     = (float*)ws;
    uint16_t* xbf    = (uint16_t*)(ws + (1 << 20));
    float*    w1last = (float*)(ws + (1 << 20) + (1 << 19));
    char*     p      = ws + (2 << 20);
    uint16_t* W1bf   = (uint16_t*)p;
    p += (size_t)VNUM * DNUM * 256 * 2;
    uint16_t* W2bf   = (uint16_t*)p;

    wx_kernel<<<dim3(16, 4), 256, 0, stream>>>(x, adj, wx);
    xcvt_kernel<<<256, 256, 0, stream>>>(x, xbf);
    w1cvt_kernel<<<(VNUM * DNUM * 257) / (4 * 256), 256, 0, stream>>>(W1, W1bf, w1last);
    w2cvt_kernel<<<(size_t)(VNUM * DNUM * DNUM) / (4 * 256), 256, 0, stream>>>(W2, W2bf);
    fused_kernel<<<4096, 512, 0, stream>>>(xbf, wx, W1bf, w1last, b1, W2bf, b2, W3, b3, out);
}